// Round 3
// baseline (299.788 us; speedup 1.0000x reference)
//
#include <hip/hip_runtime.h>

// ---------------------------------------------------------------------------
// Fusion_12867722019048: trimodal fusion MLP forward, B=65536, IN=64, H=16.
//
// Math identity (verified): all maxpooled values are products of sigmoids
// (>0), so the pools factorize:
//   fusion[a*32+m*8+l] = X[a] * Y2[m] * Z[l]
// with X = pairwise max of x_h (8), Y2 = quad max of y_h (4),
// Z = pairwise max of z_h (8).
//
// Round-3: occupancy was the limiter (grid fixed at 1024 blocks; 4 waves/blk
// -> 16 waves/CU -> VALUBusy 49%). Now 8 waves/block (NT=512), k-split 8:
// wave w owns output cols [8w,8w+8) of every 64-wide gemv and rows
// [2w,2w+2) of every 16-row projection (X[w], Z[w] = exactly one pairwise
// max per wave). 8192 waves -> 8 waves/SIMD (occupancy cap 100%).
// __launch_bounds__(512,8) keeps VGPR<=64. Weight addresses wave-uniform
// (readfirstlane wq) -> scalar s_load path. LDS [slot][lane] stride 64
// -> 2 lanes/bank = measured-free.
// ---------------------------------------------------------------------------

#define NT 512
#define NS 64   // samples per block (= lanes per wave)

__device__ __forceinline__ float fast_sigmoid(float x) {
    return __builtin_amdgcn_rcpf(1.0f + __expf(-x));
}
__device__ __forceinline__ float gate(float x, float rm) {
    // eval-mode normGate2: x * sigmoid(|x - rm|)
    return x * fast_sigmoid(fabsf(x - rm));
}
__device__ __forceinline__ float lrelu(float x) {
    return x >= 0.0f ? x : 0.01f * x;
}

// rows [r0, r0+2) of sigmoid(W(16x64) @ x + b) for this lane's sample.
// W, b wave-uniform (s_load); x per-lane (coalesced float4, L1-resident on
// the re-reads across waves: block working set 16 KB/modality < 32 KB L1).
__device__ __forceinline__ void proj2(const float* __restrict__ W,
                                      const float* __restrict__ b,
                                      const float* __restrict__ xrow,
                                      int r0, float o2[2]) {
    float s0 = 0.f, s1 = 0.f;
    const float4* x4 = reinterpret_cast<const float4*>(xrow);
    #pragma unroll
    for (int c = 0; c < 16; ++c) {
        float4 t = x4[c];
        const float* w0 = W + r0 * 64 + c * 4;        // uniform -> s_load
        const float* w1 = W + (r0 + 1) * 64 + c * 4;
        s0 = fmaf(t.x, w0[0], s0); s0 = fmaf(t.y, w0[1], s0);
        s0 = fmaf(t.z, w0[2], s0); s0 = fmaf(t.w, w0[3], s0);
        s1 = fmaf(t.x, w1[0], s1); s1 = fmaf(t.y, w1[1], s1);
        s1 = fmaf(t.z, w1[2], s1); s1 = fmaf(t.w, w1[3], s1);
    }
    o2[0] = fast_sigmoid(s0 + b[r0]);
    o2[1] = fast_sigmoid(s1 + b[r0 + 1]);
}

// Stage one path's projections for this lane's sample. Wave wq computes rows
// [2wq,2wq+2) of each 16-row projection; pairwise maxes are shared via LDS;
// returns Z[8] in registers and fills sXY rows [4wq,4wq+4).
__device__ __forceinline__ void stage_path(const float* __restrict__ Wx, const float* __restrict__ bx,
                                           const float* __restrict__ Wy, const float* __restrict__ by,
                                           const float* __restrict__ Wz, const float* __restrict__ bz,
                                           const float* __restrict__ xr, const float* __restrict__ yr,
                                           const float* __restrict__ zr,
                                           int wq, int lane,
                                           float* __restrict__ sYh, float* __restrict__ sZ,
                                           float* __restrict__ sXY, float Z[8]) {
    float t2[2];
    proj2(Wx, bx, xr, wq * 2, t2);
    const float Xw = fmaxf(t2[0], t2[1]);                 // X[wq]
    proj2(Wy, by, yr, wq * 2, t2);
    sYh[wq * NS + lane] = fmaxf(t2[0], t2[1]);            // half-pair max of y
    proj2(Wz, bz, zr, wq * 2, t2);
    sZ[wq * NS + lane] = fmaxf(t2[0], t2[1]);             // Z[wq]
    __syncthreads();
    #pragma unroll
    for (int m = 0; m < 4; ++m) {
        const float y2 = fmaxf(sYh[(2 * m) * NS + lane], sYh[(2 * m + 1) * NS + lane]);
        sXY[(wq * 4 + m) * NS + lane] = Xw * y2;          // XY[q = wq*4+m]
    }
    #pragma unroll
    for (int zz = 0; zz < 8; ++zz) Z[zz] = sZ[zz * NS + lane];
    __syncthreads();
}

// acc[k] = bias[8wq+k] + sum_q sum_ll XY[q]*Z[ll] * WT[(q*8+ll)*64 + 8wq+k]
__device__ __forceinline__ void fusion_part(const float* __restrict__ WT,
                                            const float* __restrict__ bias,
                                            int wq, int lane,
                                            const float* __restrict__ sXY,
                                            const float Z[8], float acc[8]) {
    #pragma unroll
    for (int k = 0; k < 8; ++k) acc[k] = bias[wq * 8 + k];
    #pragma unroll 1
    for (int q = 0; q < 32; ++q) {
        const float t = sXY[q * NS + lane];
        const float* wbase = WT + q * 8 * 64 + wq * 8;    // uniform -> s_load
        #pragma unroll
        for (int ll = 0; ll < 8; ++ll) {
            const float f = t * Z[ll];
            const float* w = wbase + ll * 64;
            #pragma unroll
            for (int k = 0; k < 8; ++k)
                acc[k] = fmaf(f, w[k], acc[k]);
        }
    }
}

// h[k] += sum_i sG[i][lane] * WngT[(roff+i)*64 + 8wq + k]
__device__ __forceinline__ void ng_part(const float* __restrict__ WngT, int roff,
                                        int wq, int lane,
                                        const float* __restrict__ sG, float h[8]) {
    #pragma unroll 4
    for (int i = 0; i < 64; ++i) {
        const float gi = sG[i * NS + lane];
        const float* w = WngT + (roff + i) * 64 + wq * 8; // uniform -> s_load
        #pragma unroll
        for (int k = 0; k < 8; ++k)
            h[k] = fmaf(gi, w[k], h[k]);
    }
}

__global__ __launch_bounds__(NT, 8)
void fused_fwd(const float* __restrict__ a,  const float* __restrict__ v,
               const float* __restrict__ l,  const float* __restrict__ pa,
               const float* __restrict__ pv, const float* __restrict__ pl,
               const float* __restrict__ mean,
               const float* __restrict__ Wa,  const float* __restrict__ ba,
               const float* __restrict__ Wv,  const float* __restrict__ bv,
               const float* __restrict__ Wl,  const float* __restrict__ bl,
               const float* __restrict__ Wap, const float* __restrict__ bap,
               const float* __restrict__ Wvp, const float* __restrict__ bvp,
               const float* __restrict__ Wlp, const float* __restrict__ blp,
               const float* __restrict__ bf1, const float* __restrict__ bfp1,
               const float* __restrict__ bng,
               const float* __restrict__ rm1, const float* __restrict__ rm2,
               const float* __restrict__ WfT, const float* __restrict__ WfpT,
               const float* __restrict__ WngT,
               float* __restrict__ out) {
    __shared__ float sYh[8 * NS];
    __shared__ float sZ[8 * NS];
    __shared__ float sXY[32 * NS];
    __shared__ float sG[64 * NS];

    const int tid = threadIdx.x;
    const int lane = tid & 63;
    const int wq = __builtin_amdgcn_readfirstlane(tid >> 6);  // wave-uniform
    const int sample = blockIdx.x * NS + lane;
    const size_t base = (size_t)sample * 64;

    float Z[8], acc[8], h[8];

    // ---------------- path 2 (p_a, p_v, p_l) -> fusion_2 ----------------
    stage_path(Wap, bap, Wvp, bvp, Wlp, blp, pa + base, pv + base, pl + base,
               wq, lane, sYh, sZ, sXY, Z);
    fusion_part(WfpT, bfp1, wq, lane, sXY, Z, acc);

    // gate(lrelu(fusion_2), rm1[0:64]) -> sG rows [8wq,8wq+8)
    #pragma unroll
    for (int k = 0; k < 8; ++k)
        sG[(wq * 8 + k) * NS + lane] = gate(lrelu(acc[k]), rm1[wq * 8 + k]);
    __syncthreads();

    #pragma unroll
    for (int k = 0; k < 8; ++k) h[k] = bng[wq * 8 + k];
    ng_part(WngT, 0, wq, lane, sG, h);
    __syncthreads();  // all sG reads done before overwrite

    // gated mean -> sG (rows 64..127 of the Wng input), rows [8wq,8wq+8)
    {
        const float4* m4 = reinterpret_cast<const float4*>(mean + base + wq * 8);
        #pragma unroll
        for (int c = 0; c < 2; ++c) {
            float4 t = m4[c];
            const int kk = wq * 8 + c * 4;
            sG[(kk + 0) * NS + lane] = gate(t.x, rm1[64 + kk + 0]);
            sG[(kk + 1) * NS + lane] = gate(t.y, rm1[64 + kk + 1]);
            sG[(kk + 2) * NS + lane] = gate(t.z, rm1[64 + kk + 2]);
            sG[(kk + 3) * NS + lane] = gate(t.w, rm1[64 + kk + 3]);
        }
    }
    __syncthreads();
    ng_part(WngT, 64, wq, lane, sG, h);

    // ---------------- path 1 (a, v, l) -> fusion_1 ----------------
    stage_path(Wa, ba, Wv, bv, Wl, bl, a + base, v + base, l + base,
               wq, lane, sYh, sZ, sXY, Z);
    fusion_part(WfT, bf1, wq, lane, sXY, Z, acc);

    // ---------------- epilogue ----------------
    // out[0:64] = gate(h, rm2); out[64:128] = gate(lrelu(fusion_1), rm2[64:])
    float4* o4a = reinterpret_cast<float4*>(out + (size_t)sample * 128 + wq * 8);
    #pragma unroll
    for (int c = 0; c < 2; ++c) {
        const int kk = wq * 8 + c * 4;
        float4 o;
        o.x = gate(h[c * 4 + 0], rm2[kk + 0]);
        o.y = gate(h[c * 4 + 1], rm2[kk + 1]);
        o.z = gate(h[c * 4 + 2], rm2[kk + 2]);
        o.w = gate(h[c * 4 + 3], rm2[kk + 3]);
        o4a[c] = o;
    }
    float4* o4b = reinterpret_cast<float4*>(out + (size_t)sample * 128 + 64 + wq * 8);
    #pragma unroll
    for (int c = 0; c < 2; ++c) {
        const int kk = wq * 8 + c * 4;
        float4 o;
        o.x = gate(lrelu(acc[c * 4 + 0]), rm2[64 + kk + 0]);
        o.y = gate(lrelu(acc[c * 4 + 1]), rm2[64 + kk + 1]);
        o.z = gate(lrelu(acc[c * 4 + 2]), rm2[64 + kk + 2]);
        o.w = gate(lrelu(acc[c * 4 + 3]), rm2[64 + kk + 3]);
        o4b[c] = o;
    }
}

// Pre-transpose Wf1 [64,256] -> WfT [256,64], Wfp1 likewise, Wng [64,128] ->
// WngT [128,64] so the main kernel's scalar weight loads are contiguous.
__global__ void transpose_w(const float* __restrict__ Wf1,
                            const float* __restrict__ Wfp1,
                            const float* __restrict__ Wng,
                            float* __restrict__ ws) {
    const int idx = blockIdx.x * 256 + threadIdx.x;
    if (idx < 16384) {
        const int j = idx >> 6, k = idx & 63;
        ws[idx] = Wf1[k * 256 + j];
    } else if (idx < 32768) {
        const int t = idx - 16384;
        const int j = t >> 6, k = t & 63;
        ws[16384 + t] = Wfp1[k * 256 + j];
    } else if (idx < 40960) {
        const int t = idx - 32768;
        const int i = t >> 6, k = t & 63;
        ws[32768 + t] = Wng[k * 128 + i];
    }
}

extern "C" void kernel_launch(void* const* d_in, const int* in_sizes, int n_in,
                              void* d_out, int out_size, void* d_ws, size_t ws_size,
                              hipStream_t stream) {
    const float* a    = (const float*)d_in[0];
    const float* v    = (const float*)d_in[1];
    const float* l    = (const float*)d_in[2];
    const float* pa   = (const float*)d_in[3];
    const float* pv   = (const float*)d_in[4];
    const float* pl   = (const float*)d_in[5];
    const float* mean = (const float*)d_in[6];
    const float* Wa   = (const float*)d_in[7];
    const float* ba   = (const float*)d_in[8];
    const float* Wv   = (const float*)d_in[9];
    const float* bv   = (const float*)d_in[10];
    const float* Wl   = (const float*)d_in[11];
    const float* bl   = (const float*)d_in[12];
    const float* Wap  = (const float*)d_in[13];
    const float* bap  = (const float*)d_in[14];
    const float* Wvp  = (const float*)d_in[15];
    const float* bvp  = (const float*)d_in[16];
    const float* Wlp  = (const float*)d_in[17];
    const float* blp  = (const float*)d_in[18];
    const float* Wf1  = (const float*)d_in[19];
    const float* bf1  = (const float*)d_in[20];
    const float* Wfp1 = (const float*)d_in[21];
    const float* bfp1 = (const float*)d_in[22];
    const float* Wng  = (const float*)d_in[23];
    const float* bng  = (const float*)d_in[24];
    const float* rm1  = (const float*)d_in[25];
    const float* rm2  = (const float*)d_in[26];

    float* ws = (float*)d_ws;  // needs 40960 floats = 160 KiB

    transpose_w<<<160, 256, 0, stream>>>(Wf1, Wfp1, Wng, ws);
    fused_fwd<<<65536 / NS, NT, 0, stream>>>(a, v, l, pa, pv, pl, mean,
                                             Wa, ba, Wv, bv, Wl, bl,
                                             Wap, bap, Wvp, bvp, Wlp, blp,
                                             bf1, bfp1, bng, rm1, rm2,
                                             ws, ws + 16384, ws + 32768,
                                             (float*)d_out);
}

// Round 4
// 205.018 us; speedup vs baseline: 1.4623x; 1.4623x over previous
//
#include <hip/hip_runtime.h>
#include <hip/hip_bf16.h>

// ---------------------------------------------------------------------------
// Fusion_12867722019048 on MFMA. B=65536, IN=64, H=16.
//
// Factorization (verified rounds 1-3): fusion[f = a*32 + mm*8 + l] =
//   X[a] * Y2[mm] * Z[l], X/Z pairwise maxes, Y2 quad maxes of the sigmoid
// projections (all positive, so maxpool of products factorizes).
//
// MFMA mapping (16x16x32 bf16, layouts HW-verified in learn_hip m89/m92):
//   A[m=lane&15][k=quad*8+j], B[n=lane&15][k=quad*8+j] (rows of W[n][k]),
//   D[m=quad*4+reg][n=lane&15].
// Fusion A-frag falls out of the factorization: k = t*32+quad*8+j = f with
//   a=t, mm=quad, l=j  ->  frag[j] = X[m][t]*Y2[m][quad]*Z[m][j].
//
// Wave = 16 samples, block = 4 waves = 64 samples, grid = 1024 blocks.
// Zero __syncthreads: all LDS is wave-private (pool transpose + gated-F2
// bf16 tile); DS ops from one wave execute in order.
// Weights pre-packed to bf16 frag-ordered tables in d_ws by build_frags, so
// every B-frag load is one coalesced global dwordx4 (92 KB total, L2-hot).
// ---------------------------------------------------------------------------

typedef __attribute__((ext_vector_type(8))) short short8;
typedef __attribute__((ext_vector_type(4))) float f32x4;

#define MFMA16(A, B, C) __builtin_amdgcn_mfma_f32_16x16x32_bf16((A), (B), (C), 0, 0, 0)

__device__ __forceinline__ float fast_sigmoid(float x) {
    return __builtin_amdgcn_rcpf(1.0f + __expf(-x));
}
__device__ __forceinline__ float gate(float x, float rm) {
    return x * fast_sigmoid(fabsf(x - rm));   // eval-mode normGate2
}
__device__ __forceinline__ float lrelu(float x) {
    return x >= 0.0f ? x : 0.01f * x;
}
__device__ __forceinline__ short f2bf(float f) {
    union { float f; unsigned u; } x; x.f = f;
    unsigned r = (x.u + 0x7FFF + ((x.u >> 16) & 1)) >> 16;  // RNE
    return (short)r;
}
__device__ __forceinline__ short8 pack8(const float* xs) {
    union { short8 s; __hip_bfloat162 h[4]; } u;
    #pragma unroll
    for (int i = 0; i < 4; ++i) {
        float2 t; t.x = xs[2 * i]; t.y = xs[2 * i + 1];
        u.h[i] = __float22bfloat162_rn(t);
    }
    return u.s;
}
__device__ __forceinline__ f32x4 pmax_xor(f32x4 v, int mask) {
    f32x4 r;
    #pragma unroll
    for (int i = 0; i < 4; ++i) r[i] = fmaxf(v[i], __shfl_xor(v[i], mask, 64));
    return r;
}

// sigmoid(x @ W^T + b): returns H[sample = quad*4+reg][unit = lane&15]
__device__ __forceinline__ f32x4 proj_mfma(const float* __restrict__ xbase,
                                           const short8* __restrict__ wfr,
                                           const float* __restrict__ bias,
                                           int lane) {
    const int m = lane & 15, quad = lane >> 4;
    f32x4 acc; acc[0] = acc[1] = acc[2] = acc[3] = 0.0f;
    #pragma unroll
    for (int t = 0; t < 2; ++t) {
        const float4* p = (const float4*)(xbase + m * 64 + t * 32 + quad * 8);
        float4 u0 = p[0], u1 = p[1];
        float xs[8] = {u0.x, u0.y, u0.z, u0.w, u1.x, u1.y, u1.z, u1.w};
        acc = MFMA16(pack8(xs), wfr[t * 64 + lane], acc);
    }
    const float bn = bias[m];
    f32x4 h;
    #pragma unroll
    for (int r = 0; r < 4; ++r) h[r] = fast_sigmoid(acc[r] + bn);
    return h;
}

// Pool + transpose into wave-private LDS: X8T[8][16], Y2T[4][16], Z8T[8][16].
// Duplicate-lane writes hit the same address with the same value (benign).
__device__ __forceinline__ void stage_pools(f32x4 hx, f32x4 hy, f32x4 hz, int lane,
                                            float* __restrict__ sX,
                                            float* __restrict__ sY,
                                            float* __restrict__ sZ) {
    const int quad = lane >> 4, ln = lane & 15;
    f32x4 X = pmax_xor(hx, 1);
    f32x4 Y = pmax_xor(pmax_xor(hy, 1), 2);
    f32x4 Z = pmax_xor(hz, 1);
    #pragma unroll
    for (int r = 0; r < 4; ++r) {
        const int sm = quad * 4 + r;
        sX[(ln >> 1) * 16 + sm] = X[r];
        sY[(ln >> 2) * 16 + sm] = Y[r];
        sZ[(ln >> 1) * 16 + sm] = Z[r];
    }
}

// acc[nt] = D tile [16 samples][16 cols], cols nt*16+lane&15; K=256 in 8 steps.
__device__ __forceinline__ void fusion_mfma(const short8* __restrict__ wfr,
                                            const float* __restrict__ bias,
                                            const float* __restrict__ sX,
                                            const float* __restrict__ sY,
                                            const float* __restrict__ sZ,
                                            int lane, f32x4 acc[4]) {
    const int m = lane & 15, quad = lane >> 4;
    #pragma unroll
    for (int nt = 0; nt < 4; ++nt) {
        const float bb = bias[nt * 16 + m];
        acc[nt][0] = acc[nt][1] = acc[nt][2] = acc[nt][3] = bb;
    }
    float zr[8];
    #pragma unroll
    for (int j = 0; j < 8; ++j) zr[j] = sZ[j * 16 + m];
    const float yq = sY[quad * 16 + m];
    #pragma unroll
    for (int t = 0; t < 8; ++t) {
        const float xy = sX[t * 16 + m] * yq;
        float p[8];
        #pragma unroll
        for (int j = 0; j < 8; ++j) p[j] = xy * zr[j];
        const short8 af = pack8(p);
        #pragma unroll
        for (int nt = 0; nt < 4; ++nt)
            acc[nt] = MFMA16(af, wfr[(t * 4 + nt) * 64 + lane], acc[nt]);
    }
}

__global__ __launch_bounds__(256, 4)
void fused_fwd(const float* __restrict__ a,  const float* __restrict__ v,
               const float* __restrict__ l,  const float* __restrict__ pa,
               const float* __restrict__ pv, const float* __restrict__ pl,
               const float* __restrict__ mean,
               const float* __restrict__ ba,  const float* __restrict__ bv_,
               const float* __restrict__ bl_, const float* __restrict__ bap,
               const float* __restrict__ bvp, const float* __restrict__ blp,
               const float* __restrict__ bf1, const float* __restrict__ bfp1,
               const float* __restrict__ bng,
               const float* __restrict__ rm1, const float* __restrict__ rm2,
               const short* __restrict__ ws, float* __restrict__ out) {
    __shared__ __align__(16) float sPool[4 * 320];   // per wave: X8T|Y2T|Z8T
    __shared__ __align__(16) short sF2[4 * 1280];    // per wave: [16][80] bf16

    const int tid = threadIdx.x;
    const int lane = tid & 63;
    const int w = tid >> 6;
    const int m = lane & 15;
    const int quad = lane >> 4;
    const int srow0 = blockIdx.x * 64 + w * 16;      // wave's first sample

    float* sX = sPool + w * 320;
    float* sY = sX + 128;
    float* sZ = sY + 64;
    short* sF = sF2 + w * 1280;

    const short8* projFr = (const short8*)ws;             // 6 x 128 frags
    const short8* wfFr   = (const short8*)(ws + 6144);    // 32 x 64
    const short8* wfpFr  = (const short8*)(ws + 22528);   // 32 x 64
    const short8* wngFr  = (const short8*)(ws + 38912);   // 16 x 64

    // ---------------- path 2 (p_a, p_v, p_l) -> fusion_2 ----------------
    {
        f32x4 hx = proj_mfma(pa + (size_t)srow0 * 64, projFr + 3 * 128, bap, lane);
        f32x4 hy = proj_mfma(pv + (size_t)srow0 * 64, projFr + 4 * 128, bvp, lane);
        f32x4 hz = proj_mfma(pl + (size_t)srow0 * 64, projFr + 5 * 128, blp, lane);
        stage_pools(hx, hy, hz, lane, sX, sY, sZ);
    }
    f32x4 f2[4];
    fusion_mfma(wfpFr, bfp1, sX, sY, sZ, lane, f2);

    // gate(lrelu(fusion_2), rm1[0:64]) -> wave-private bf16 tile [16][80]
    #pragma unroll
    for (int nt = 0; nt < 4; ++nt) {
        const float r1 = rm1[nt * 16 + m];
        #pragma unroll
        for (int r = 0; r < 4; ++r) {
            const float g = gate(lrelu(f2[nt][r]), r1);
            sF[(quad * 4 + r) * 80 + nt * 16 + m] = f2bf(g);
        }
    }

    // ---------------- ng gemm: h = concat(F2g, gated mean) @ Wng^T + bng ----
    f32x4 h[4];
    #pragma unroll
    for (int nt = 0; nt < 4; ++nt) {
        const float bb = bng[nt * 16 + m];
        h[nt][0] = h[nt][1] = h[nt][2] = h[nt][3] = bb;
    }
    #pragma unroll
    for (int t = 0; t < 2; ++t) {   // k = 0..63 from F2g tile (LDS, 16B aligned)
        const short8 af = *(const short8*)(sF + m * 80 + t * 32 + quad * 8);
        #pragma unroll
        for (int nt = 0; nt < 4; ++nt)
            h[nt] = MFMA16(af, wngFr[(t * 4 + nt) * 64 + lane], h[nt]);
    }
    #pragma unroll
    for (int t2 = 0; t2 < 2; ++t2) {  // k = 64..127 from gated mean (global)
        const float4* mp = (const float4*)(mean + (size_t)(srow0 + m) * 64 + t2 * 32 + quad * 8);
        float4 u0 = mp[0], u1 = mp[1];
        const float4* rp = (const float4*)(rm1 + 64 + t2 * 32 + quad * 8);
        float4 r0 = rp[0], r1 = rp[1];
        float g[8] = { gate(u0.x, r0.x), gate(u0.y, r0.y), gate(u0.z, r0.z), gate(u0.w, r0.w),
                       gate(u1.x, r1.x), gate(u1.y, r1.y), gate(u1.z, r1.z), gate(u1.w, r1.w) };
        const short8 af = pack8(g);
        #pragma unroll
        for (int nt = 0; nt < 4; ++nt)
            h[nt] = MFMA16(af, wngFr[((2 + t2) * 4 + nt) * 64 + lane], h[nt]);
    }

    // ---------------- path 1 (a, v, l) -> fusion_1 ----------------
    {
        f32x4 hx = proj_mfma(a + (size_t)srow0 * 64, projFr + 0 * 128, ba, lane);
        f32x4 hy = proj_mfma(v + (size_t)srow0 * 64, projFr + 1 * 128, bv_, lane);
        f32x4 hz = proj_mfma(l + (size_t)srow0 * 64, projFr + 2 * 128, bl_, lane);
        stage_pools(hx, hy, hz, lane, sX, sY, sZ);
    }
    f32x4 f1[4];
    fusion_mfma(wfFr, bf1, sX, sY, sZ, lane, f1);

    // ---------------- epilogue: gate with rm2, store ----------------
    #pragma unroll
    for (int nt = 0; nt < 4; ++nt) {
        const float r2a = rm2[nt * 16 + m];
        const float r2b = rm2[64 + nt * 16 + m];
        #pragma unroll
        for (int r = 0; r < 4; ++r) {
            const size_t row = (size_t)(srow0 + quad * 4 + r) * 128;
            out[row + nt * 16 + m]      = gate(h[nt][r], r2a);
            out[row + 64 + nt * 16 + m] = gate(lrelu(f1[nt][r]), r2b);
        }
    }
}

// Pack all weights into bf16 frag-ordered tables:
//   frag element for (t, nt, lane, j): row = nt*16 + (lane&15),
//   col = t*32 + (lane>>4)*8 + j  -> B[n][k] rows of each W.
// Layout (shorts): [0,6144) six 16x64 projs (Wa,Wv,Wl,Wap,Wvp,Wlp);
// [6144,22528) Wf1; [22528,38912) Wfp1; [38912,47104) Wng.
__global__ void build_frags(const float* __restrict__ Wa,  const float* __restrict__ Wv,
                            const float* __restrict__ Wl,  const float* __restrict__ Wap,
                            const float* __restrict__ Wvp, const float* __restrict__ Wlp,
                            const float* __restrict__ Wf1, const float* __restrict__ Wfp1,
                            const float* __restrict__ Wng, short* __restrict__ ws) {
    const int i = blockIdx.x * 256 + threadIdx.x;
    if (i >= 47104) return;
    float val;
    if (i < 6144) {
        const float* W[6] = {Wa, Wv, Wl, Wap, Wvp, Wlp};
        const int mi = i >> 10, r = i & 1023;
        const int t = r >> 9, lane = (r >> 3) & 63, j = r & 7;
        val = W[mi][(lane & 15) * 64 + t * 32 + (lane >> 4) * 8 + j];
    } else if (i < 38912) {
        int r = i - 6144;
        const float* W = (r < 16384) ? Wf1 : Wfp1;
        r &= 16383;
        const int tn = r >> 9, lane = (r >> 3) & 63, j = r & 7;
        const int t = tn >> 2, nt = tn & 3;
        val = W[(nt * 16 + (lane & 15)) * 256 + t * 32 + (lane >> 4) * 8 + j];
    } else {
        const int r = i - 38912;
        const int tn = r >> 9, lane = (r >> 3) & 63, j = r & 7;
        const int t = tn >> 2, nt = tn & 3;
        val = Wng[(nt * 16 + (lane & 15)) * 128 + t * 32 + (lane >> 4) * 8 + j];
    }
    ws[i] = f2bf(val);
}

extern "C" void kernel_launch(void* const* d_in, const int* in_sizes, int n_in,
                              void* d_out, int out_size, void* d_ws, size_t ws_size,
                              hipStream_t stream) {
    const float* a    = (const float*)d_in[0];
    const float* v    = (const float*)d_in[1];
    const float* l    = (const float*)d_in[2];
    const float* pa   = (const float*)d_in[3];
    const float* pv   = (const float*)d_in[4];
    const float* pl   = (const float*)d_in[5];
    const float* mean = (const float*)d_in[6];
    const float* Wa   = (const float*)d_in[7];
    const float* ba   = (const float*)d_in[8];
    const float* Wv   = (const float*)d_in[9];
    const float* bv   = (const float*)d_in[10];
    const float* Wl   = (const float*)d_in[11];
    const float* bl   = (const float*)d_in[12];
    const float* Wap  = (const float*)d_in[13];
    const float* bap  = (const float*)d_in[14];
    const float* Wvp  = (const float*)d_in[15];
    const float* bvp  = (const float*)d_in[16];
    const float* Wlp  = (const float*)d_in[17];
    const float* blp  = (const float*)d_in[18];
    const float* Wf1  = (const float*)d_in[19];
    const float* bf1  = (const float*)d_in[20];
    const float* Wfp1 = (const float*)d_in[21];
    const float* bfp1 = (const float*)d_in[22];
    const float* Wng  = (const float*)d_in[23];
    const float* bng  = (const float*)d_in[24];
    const float* rm1  = (const float*)d_in[25];
    const float* rm2  = (const float*)d_in[26];

    short* ws = (short*)d_ws;  // 47104 shorts = 92 KiB

    build_frags<<<184, 256, 0, stream>>>(Wa, Wv, Wl, Wap, Wvp, Wlp,
                                         Wf1, Wfp1, Wng, ws);
    fused_fwd<<<1024, 256, 0, stream>>>(a, v, l, pa, pv, pl, mean,
                                        ba, bv, bl, bap, bvp, blp,
                                        bf1, bfp1, bng, rm1, rm2,
                                        ws, (float*)d_out);
}